// Round 6
// baseline (952.276 us; speedup 1.0000x reference)
//
#include <hip/hip_runtime.h>
#include <math.h>

typedef short bf16x8 __attribute__((ext_vector_type(8)));
typedef float f32x4 __attribute__((ext_vector_type(4)));
typedef unsigned short u16;
typedef unsigned int u32;

// float-region offsets in ws
#define WSUMS 0
#define TOTWS 1
#define WSUM_OFF 2
#define TOTW_OFF 8194
#define SCL_F 16386
#define WB_BYTE 98432      // start of bf16/u16 region (byte offset)

// u16-region offsets
#define GWI_U 0            // [384][32]   gru Wih (cols 0..29, pad 0)
#define GWH_U 12288        // [384][128]  gru Whh
#define EO_U  61440        // [7][512][256]  enc (Wih|Whh)
#define DO_U  978944       // [512][320]  dec packed
#define XG_U  1142784      // [7][8192][24][16] gru x feats
#define XD_U  23162880     // [8192][24][16]    dec x feats

// exp2 prescale: v_exp_f32 computes 2^x, so fold log2(e) (sigmoid gates) /
// 2*log2(e) (tanh gates) into the weights+biases at prep time.
#define L2E 1.4426950408889634f
#define T2E 2.8853900817779268f

__constant__ int cLAG[8] = {144,120,96,72,48,24,0,168};

// rcp instead of IEEE divide (no -ffast-math in harness): ~1ulp, invisible in bf16.
__device__ __forceinline__ float sig2(float x){   // x already *log2e
  return __builtin_amdgcn_rcpf(1.0f+__builtin_amdgcn_exp2f(-x));
}
__device__ __forceinline__ float th2(float x){    // x already *2log2e
  return __builtin_fmaf(-2.0f, __builtin_amdgcn_rcpf(__builtin_amdgcn_exp2f(x)+1.0f), 1.0f);
}
__device__ __forceinline__ float thc(float x){    // unscaled arg (cell state)
  return th2(x*T2E);
}
__device__ __forceinline__ u16 f2b(float x){ u32 u=__float_as_uint(x); return (u16)((u + 0x7fffu + ((u>>16)&1u))>>16); }
__device__ __forceinline__ float b2f(u16 v){ return __uint_as_float(((u32)v)<<16); }
// packed f32->bf16 (RNE, identical to f2b) - 1 instr for 2 values
__device__ __forceinline__ u32 f2b_pk(float lo, float hi){
  u32 r; asm("v_cvt_pk_bf16_f32 %0, %1, %2" : "=v"(r) : "v"(lo), "v"(hi)); return r;
}
__device__ __forceinline__ void pin(bf16x8 &x){
  f32x4 t = __builtin_bit_cast(f32x4, x);
  asm volatile("" : "+v"(t));
  x = __builtin_bit_cast(bf16x8, t);
}

#define MFMA(a,b,c) __builtin_amdgcn_mfma_f32_16x16x32_bf16(a,b,c,0,0,0)

__global__ void scale_kernel(const float* __restrict__ tgt,
                             const float* __restrict__ obs,
                             float* __restrict__ ws)
{
  __shared__ float s1[256], s2[256];
  int b = blockIdx.x*256 + threadIdx.x;
  float wsum=0.f, totw=0.f;
  const float* tr = tgt + b*336 + 168;
  const float* wr = obs + b*336 + 168;
  for(int t=0;t<168;t++){ float w=wr[t]; wsum += fabsf(tr[t])*w; totw += w; }
  ws[WSUM_OFF + b] = wsum;
  ws[TOTW_OFF + b] = totw;
  s1[threadIdx.x]=wsum; s2[threadIdx.x]=totw;
  __syncthreads();
  for(int s=128;s>0;s>>=1){
    if(threadIdx.x<s){ s1[threadIdx.x]+=s1[threadIdx.x+s]; s2[threadIdx.x]+=s2[threadIdx.x+s]; }
    __syncthreads();
  }
  if(threadIdx.x==0){ atomicAdd(&ws[WSUMS], s1[0]); atomicAdd(&ws[TOTWS], s2[0]); }
}

// Gate rows: [0,128)=r/i sig, [128,256)=z/f sig, [256,384)=n/g tanh, [384,512)=o sig.
// sigmoid rows *L2E, tanh rows *T2E (see sig2/th2).
__global__ void prep_w(const float* __restrict__ gWih, const float* __restrict__ gWhh,
                       const float* __restrict__ eWih, const float* __restrict__ eWhh,
                       const float* __restrict__ dWih, const float* __restrict__ dWhh,
                       float* __restrict__ ws)
{
  u16* WU = (u16*)((char*)ws + WB_BYTE);
  int tid = blockIdx.x*blockDim.x + threadIdx.x;
  int nt = gridDim.x*blockDim.x;
  for(int i=tid;i<12288;i+=nt){ int n=i>>5,k=i&31;
    float s=((n>>7)==2)?T2E:L2E;
    WU[GWI_U+i]=(k<30)?f2b(gWih[n*30+k]*s):(u16)0; }
  for(int i=tid;i<49152;i+=nt){ int n=i>>7,k=i&127;
    float s=((n>>7)==2)?T2E:L2E;
    WU[GWH_U+i]=f2b(gWhh[n*128+k]*s); }
  for(int i=tid;i<917504;i+=nt){
    int s=i>>17,r2=i&131071,n=r2>>8,k=r2&255;
    float sc=((n>>7)==2)?T2E:L2E;
    float v=(k<128)?eWih[(s*512+n)*128+k]:eWhh[(s*512+n)*128+(k-128)];
    WU[EO_U+i]=f2b(v*sc);
  }
  for(int i=tid;i<163840;i+=nt){
    int n=i/320, k=i-n*320; float v;
    float sc=((n>>7)==2)?T2E:L2E;
    if(k<128)       v=dWih[n*180+30+k];
    else if(k<136)  v=dWih[n*180+(k-128)];
    else if(k<140)  v=dWih[n*180+8+(k-136)];
    else if(k<144)  v=dWih[n*180+158+(k-140)];
    else if(k<162)  v=dWih[n*180+12+(k-144)];
    else if(k<180)  v=dWih[n*180+162+(k-162)];
    else if(k<192)  v=0.f;
    else            v=dWhh[n*128+(k-192)];
    WU[DO_U+i]=f2b(v*sc);
  }
}

__global__ void prep_x(const float* __restrict__ tgt, const float* __restrict__ ptf,
                       const float* __restrict__ ftf, float* __restrict__ ws)
{
  __shared__ float inv_l[64];
  u16* WU = (u16*)((char*)ws + WB_BYTE);
  const int tid = threadIdx.x;
  const int b0 = blockIdx.x*64;
  if(tid<64){
    int b=b0+tid;
    float wsumv=ws[WSUM_OFF+b], totw=ws[TOTW_OFF+b];
    float def=ws[WSUMS]/fmaxf(ws[TOTWS],1.f);
    float sc=fmaxf(1e-10f,(wsumv>0.f)?wsumv/fmaxf(totw,1.f):def);
    ws[SCL_F+b]=sc; inv_l[tid]=1.f/sc;
  }
  __syncthreads();
  for(int idx=tid; idx<64*168; idx+=256){
    int bl=idx/168, gt=idx-bl*168; int b=b0+bl;
    float iv=inv_l[bl];
    __align__(16) u16 row[16];
    #pragma unroll
    for(int j=0;j<8;j++) row[j]=f2b(tgt[b*336+cLAG[j]+gt]*iv);
    const float* pp=ptf+((size_t)(b*336+168+gt))*4;
    #pragma unroll
    for(int j=0;j<4;j++) row[8+j]=f2b(pp[j]);
    row[12]=row[13]=row[14]=row[15]=0;
    int seg=gt/24, t=gt-seg*24;
    u16* dst=WU+XG_U+(((size_t)seg*8192+b)*24+t)*16;
    *(uint4*)dst=*(const uint4*)row; *(uint4*)(dst+8)=*(const uint4*)(row+8);
  }
  for(int idx=tid; idx<64*24; idx+=256){
    int bl=idx/24, t=idx-bl*24; int b=b0+bl;
    float iv=inv_l[bl];
    __align__(16) u16 row[16];
    #pragma unroll
    for(int j=0;j<8;j++) row[j]=f2b(tgt[b*336+cLAG[j]+t]*iv);
    #pragma unroll
    for(int j=0;j<4;j++) row[8+j]=f2b(ptf[((size_t)(b*336+168+t))*4+j]);
    #pragma unroll
    for(int j=0;j<4;j++) row[12+j]=f2b(ftf[b*96+t*4+j]);
    u16* dst=WU+XD_U+((size_t)b*24+t)*16;
    *(uint4*)dst=*(const uint4*)row; *(uint4*)(dst+8)=*(const uint4*)(row+8);
  }
}

// beta(r,t) = (t>>2)*64 + r*4 + (t&3): encbuf row index (t-group-major)
// Direct strided A-frag reads from encbuf (row = tb + l15*4): dword base
// == (l15&1)*16 + quad*4 (mod 32) -> 8 disjoint 4-bank spans x 8 lanes =
// 8-cycle b128 minimum, conflict-free (same distribution as the old Ab copy).
// LDS (~140 KB) caps residency at 1 block/CU = 2 waves/EU. The v252-v255 entry
// clobber statically forces a 256-VGPR allocation (the allocator otherwise
// targets 4 waves/EU -> 128 regs -> weight spills, measured r3/r5/r6/r7).
__global__ __launch_bounds__(512,2)
__attribute__((amdgpu_waves_per_eu(2,2)))
void deepar_main(const int* __restrict__ cat, const float* __restrict__ sreal,
                 const float* __restrict__ emb,
                 const float* __restrict__ gbih, const float* __restrict__ gbhh,
                 const float* __restrict__ encb, const float* __restrict__ decb,
                 const float* __restrict__ outW, const float* __restrict__ outb,
                 float* __restrict__ ws, float* __restrict__ out)
{
  asm volatile("" ::: "v252","v253","v254","v255");   // force 256-VGPR allocation

  const u16* __restrict__ WU=(const u16*)((const char*)ws+WB_BYTE);

  __shared__ __align__(16) u16 encbuf[384*136];   // enc_out / hv, in place (beta rows)
  __shared__ __align__(16) u16 Xast[4][64*40];    // GRU x tile, depth-2 prefetch ring
  __shared__ __align__(16) u16 Xdast[2][16*72];   // dec extra feats, double-buffered
  __shared__ __align__(16) u16 hstash[2][16*136]; // recurrent h, double-buffered
  __shared__ u16 statb[16][18];
  __shared__ float scl_s[16];
  __shared__ float outw_s[128];
  __shared__ float red[16][8];
  __shared__ float outb_s;

  const int tid=threadIdx.x;
  const int b0=blockIdx.x*16;
  const int wv=tid>>6, lane=tid&63, quad=lane>>4, l15=lane&15;

  // GRU x-tile stage for global chunk gc into Xast[gc&3], issued 2 chunks ahead:
  // buffer (gc+2)&3 was last READ by compute(gc-2); barriers (gc-2),(gc-1)
  // separate -> race-free. Depth 2 gives ~2 chunks (~2000cy) to cover HBM latency.
  auto stageX = [&](int gc){
    if(tid<128 && gc<42){
      int sg=gc/6, cc=gc-sg*6;
      int a=tid>>1;
      u16* Xb=&Xast[gc&3][0];
      const u16* src=WU+XG_U+(((size_t)sg*8192+b0+(a>>2))*24+4*cc+(a&3))*16;
      if(tid&1) *(uint2*)(Xb+a*40+8)=*(const uint2*)(src+8);
      else      *(uint4*)(Xb+a*40)  =*(const uint4*)src;
    }
  };

  if(tid<16) scl_s[tid]=ws[SCL_F+b0+tid];
  if(tid<128) outw_s[tid]=outW[tid];
  if(tid==128) outb_s=outb[0];
  if(tid>=256){ int q=tid-256; int r=q>>4,k=q&15; statb[r][k]=f2b(emb[cat[b0+r]*16+k]); }
  { const uint4 z4={0,0,0,0};
    for(int i=tid;i<6528;i+=512) *(uint4*)(encbuf+i*8)=z4;        // 6528*8 = 384*136
    for(int i=tid;i<544;i+=512)  *(uint4*)(&hstash[0][0]+i*8)=z4; // 544*8 = 2*16*136
  }
  __syncthreads();
  if(tid<16){ statb[tid][16]=f2b(sreal[b0+tid]); statb[tid][17]=f2b(logf(scl_s[tid])); }
  __syncthreads();
  // prebuild t-invariant columns of GRU / dec A-tiles (all ring buffers)
  for(int i=tid;i<1280;i+=512){ int a=i/20, k=i-a*20+12;
    u16 v=(k<30)?statb[a>>2][k-12]:(u16)0;
    Xast[0][a*40+k]=v; Xast[1][a*40+k]=v; Xast[2][a*40+k]=v; Xast[3][a*40+k]=v; }
  for(int i=tid;i<896;i+=512){ int rr=i/56, k=i-rr*56+16;
    u16 v; if(k<34) v=statb[rr][k-16]; else if(k<52) v=statb[rr][k-34]; else v=0;
    Xdast[0][rr*72+k]=v; Xdast[1][rr*72+k]=v; }
  stageX(0); stageX(1);   // prologue prefetch (cols 0-11, disjoint from prebuild 12-31)
  __syncthreads();

  float gbi[3], gbh[3];
  #pragma unroll
  for(int j=0;j<3;j++){ int nb=(wv+j*8)*16+l15;
    float s=(j==2)?T2E:L2E;
    gbi[j]=gbih[nb]*s; gbh[j]=gbhh[nb]*s; }
  // r/z gates only ever consumed as (ih+hh): merged bias. Bias f32x4 vectors
  // seed the FIRST MFMA's C operand -> no per-chunk accumulator-init movs.
  const float gbr=gbi[0]+gbh[0], gbz=gbi[1]+gbh[1];
  const f32x4 b4r ={gbr,gbr,gbr,gbr};
  const f32x4 b4z ={gbz,gbz,gbz,gbz};
  const f32x4 b4i2={gbi[2],gbi[2],gbi[2],gbi[2]};
  const f32x4 b4h2={gbh[2],gbh[2],gbh[2],gbh[2]};

  float cst[4]={0.f,0.f,0.f,0.f};
  const int hc=wv*16+l15;
  int p=0;                                  // hstash parity

  for(int seg=0;seg<7;seg++){
    // ---- GRU weights: load + pin (live this phase only) ----
    bf16x8 gwi[3]; bf16x8 gwh[3][4];
    #pragma unroll
    for(int j=0;j<3;j++){
      int nb=(wv+j*8)*16+l15;
      gwi[j]=*(const bf16x8*)(WU+GWI_U+nb*32+quad*8); pin(gwi[j]);
      #pragma unroll
      for(int kt=0;kt<4;kt++){ gwh[j][kt]=*(const bf16x8*)(WU+GWH_U+nb*128+kt*32+quad*8); pin(gwh[j][kt]); }
    }

    // ============ GRU: 6 chunks x 64 A-rows, in place, 1 barrier/chunk ============
    for(int c=0;c<6;c++){
      stageX(seg*6+c+2);                    // prefetch 2 chunks ahead
      const u16* Xb = &Xast[(seg*6+c)&3][0];

      f32x4 g01[2][4], a2[4], h2[4];
      #pragma unroll
      for(int mt=0;mt<4;mt++){
        bf16x8 af=*(const bf16x8*)(Xb+(mt*16+l15)*40+quad*8);
        g01[0][mt]=MFMA(af,gwi[0],b4r);
        g01[1][mt]=MFMA(af,gwi[1],b4z);
        a2[mt]   =MFMA(af,gwi[2],b4i2);
      }
      const u16* ebase=encbuf+(size_t)(c*64)*136;
      #pragma unroll
      for(int kt=0;kt<4;kt++)
        #pragma unroll
        for(int mt=0;mt<4;mt++){
          bf16x8 af=*(const bf16x8*)(ebase+(mt*16+l15)*136+kt*32+quad*8);
          g01[0][mt]=MFMA(af,gwh[0][kt],g01[0][mt]);
          g01[1][mt]=MFMA(af,gwh[1][kt],g01[1][mt]);
          h2[mt]   =MFMA(af,gwh[2][kt],(kt==0)?b4h2:h2[mt]);
        }
      u16 hv16[4][4];
      #pragma unroll
      for(int mt=0;mt<4;mt++){
        float hv[4];
        #pragma unroll
        for(int reg=0;reg<4;reg++){
          int a=mt*16+quad*4+reg;
          float rg=sig2(g01[0][mt][reg]);
          float zg=sig2(g01[1][mt][reg]);
          float hp=b2f(encbuf[(c*64+a)*136+hc]);
          float nn=th2(__builtin_fmaf(rg,h2[mt][reg],a2[mt][reg]));
          hv[reg]=__builtin_fmaf(zg,hp-nn,nn);
        }
        u32 p01=f2b_pk(hv[0],hv[1]), p23=f2b_pk(hv[2],hv[3]);
        hv16[mt][0]=(u16)p01; hv16[mt][1]=(u16)(p01>>16);
        hv16[mt][2]=(u16)p23; hv16[mt][3]=(u16)(p23>>16);
      }
      __syncthreads();   // all reads of rows c done before in-place overwrite
      #pragma unroll
      for(int mt=0;mt<4;mt++)
        #pragma unroll
        for(int reg=0;reg<4;reg++)
          encbuf[(c*64+mt*16+quad*4+reg)*136+hc]=hv16[mt][reg];
    }

    // ===== encoder LSTM: resident weights, 24 steps, pipelined A-half =====
    bf16x8 we[4][8]; f32x4 b4e[4];
    #pragma unroll
    for(int j=0;j<4;j++){
      int nb=(wv+j*8)*16+l15;
      float b=encb[seg*512+nb]*((j==2)?T2E:L2E);
      b4e[j]=(f32x4){b,b,b,b};
      #pragma unroll
      for(int kt=0;kt<8;kt++){
        we[j][kt]=*(const bf16x8*)(WU+EO_U+(size_t)seg*131072+nb*256+kt*32+quad*8);
        pin(we[j][kt]);
      }
    }
    // accA(t) = bias + A-half, computed pre-barrier reading rows(t) direct.
    // Safe: rows(t) are only written by step t's own h-write (post-barrier(t)).
    f32x4 accA[4];
    {
      const u16* Ar=encbuf+(size_t)(l15*4)*136;   // tb(0)=0
      #pragma unroll
      for(int kt=0;kt<4;kt++){
        bf16x8 af=*(const bf16x8*)(Ar+kt*32+quad*8);
        #pragma unroll
        for(int j=0;j<4;j++) accA[j]=MFMA(af,we[j][kt],(kt==0)?b4e[j]:accA[j]);
      }
    }
    for(int t=0;t<24;t++){
      __syncthreads();                       // h_{t-1} (hstash[p]) visible
      const u16* Hb=&hstash[p][0];
      f32x4 acc[4];
      #pragma unroll
      for(int kt=0;kt<4;kt++){
        bf16x8 af=*(const bf16x8*)(Hb+l15*136+kt*32+quad*8);
        #pragma unroll
        for(int j=0;j<4;j++) acc[j]=MFMA(af,we[j][kt+4],(kt==0)?accA[j]:acc[j]);
      }
      // prefetch+compute A-half of t+1 (independent of act; overlaps it)
      if(t<23){
        int tb1=((t+1)>>2)*64+((t+1)&3);
        const u16* Ar=encbuf+(size_t)(tb1+l15*4)*136;
        #pragma unroll
        for(int kt=0;kt<4;kt++){
          bf16x8 af=*(const bf16x8*)(Ar+kt*32+quad*8);
          #pragma unroll
          for(int j=0;j<4;j++) accA[j]=MFMA(af,we[j][kt],(kt==0)?b4e[j]:accA[j]);
        }
      }
      u16 hnew[4];
      { float hf[4];
        #pragma unroll
        for(int reg=0;reg<4;reg++){
          float ig=sig2(acc[0][reg]),fg=sig2(acc[1][reg]);
          float gg=th2(acc[2][reg]), og=sig2(acc[3][reg]);
          float c_=__builtin_fmaf(fg,cst[reg],ig*gg); cst[reg]=c_;
          hf[reg]=og*thc(c_);
        }
        u32 p01=f2b_pk(hf[0],hf[1]), p23=f2b_pk(hf[2],hf[3]);
        hnew[0]=(u16)p01; hnew[1]=(u16)(p01>>16);
        hnew[2]=(u16)p23; hnew[3]=(u16)(p23>>16);
      }
      int pn=p^1;
      int tb=(t>>2)*64+(t&3);
      u16* Hw=&hstash[pn][0];
      #pragma unroll
      for(int reg=0;reg<4;reg++){
        int row=quad*4+reg;
        Hw[row*136+hc]=hnew[reg];            // opposite buffer: no read hazard
        encbuf[(tb+row*4)*136+hc]=hnew[reg]; // rows(t): nobody reads them this step
      }
      p=pn;
    }
  }

  // ================= decoder LSTM + projection =================
  bf16x8 wd[4][10]; f32x4 b4d[4];
  #pragma unroll
  for(int j=0;j<4;j++){
    int nb=(wv+j*8)*16+l15;
    float b=decb[nb]*((j==2)?T2E:L2E);
    b4d[j]=(f32x4){b,b,b,b};
    #pragma unroll
    for(int kt=0;kt<10;kt++){
      wd[j][kt]=*(const bf16x8*)(WU+DO_U+nb*320+kt*32+quad*8);
      pin(wd[j][kt]);
    }
  }
  // prologue: stage Xd(0); barrier also publishes enc's final h-writes
  if(tid>=256 && tid<288){ int q=tid-256; int rr=q>>1;
    const u16* src=WU+XD_U+((size_t)(b0+rr)*24+0)*16;
    u16* Xw=&Xdast[0][0];
    if(q&1) *(uint4*)(Xw+rr*72+8)=*(const uint4*)(src+8);
    else    *(uint4*)(Xw+rr*72)  =*(const uint4*)src; }
  __syncthreads();
  for(int t=0;t<24;t++){
    int tb=(t>>2)*64+(t&3);
    const u16* Ar=encbuf+(size_t)(tb+l15*4)*136;   // read-only in dec: no ordering needed
    const u16* Xd=&Xdast[t&1][0];
    const u16* Hb=&hstash[p][0];
    f32x4 acc[4];
    #pragma unroll
    for(int kt=0;kt<10;kt++){
      bf16x8 af=(kt<4)? *(const bf16x8*)(Ar+kt*32+quad*8)
              :(kt<6)? *(const bf16x8*)(Xd+l15*72+(kt-4)*32+quad*8)
                     : *(const bf16x8*)(Hb+l15*136+(kt-6)*32+quad*8);
      #pragma unroll
      for(int j=0;j<4;j++) acc[j]=MFMA(af,wd[j][kt],(kt==0)?b4d[j]:acc[j]);
    }
    // prefetch Xd(t+1) into opposite buffer: last reader was MFMA(t-1),
    // two barriers back -> race-free
    if(t<23 && tid>=256 && tid<288){ int q=tid-256; int rr=q>>1;
      const u16* src=WU+XD_U+((size_t)(b0+rr)*24+t+1)*16;
      u16* Xw=&Xdast[(t+1)&1][0];
      if(q&1) *(uint4*)(Xw+rr*72+8)=*(const uint4*)(src+8);
      else    *(uint4*)(Xw+rr*72)  =*(const uint4*)src; }
    u16 hnew[4];
    { float hf[4];
      #pragma unroll
      for(int reg=0;reg<4;reg++){
        float ig=sig2(acc[0][reg]),fg=sig2(acc[1][reg]);
        float gg=th2(acc[2][reg]), og=sig2(acc[3][reg]);
        float c_=__builtin_fmaf(fg,cst[reg],ig*gg); cst[reg]=c_;
        hf[reg]=og*thc(c_);
      }
      u32 p01=f2b_pk(hf[0],hf[1]), p23=f2b_pk(hf[2],hf[3]);
      hnew[0]=(u16)p01; hnew[1]=(u16)(p01>>16);
      hnew[2]=(u16)p23; hnew[3]=(u16)(p23>>16);
    }
    int pn=p^1;
    #pragma unroll
    for(int reg=0;reg<4;reg++)
      hstash[pn][(quad*4+reg)*136+hc]=hnew[reg];
    __syncthreads();      // projection needs the full new h row (+ Xd stage done)
    if(tid<128){ int row=tid>>3,g=tid&7; float s=0.f;
      #pragma unroll
      for(int i=0;i<16;i++) s+=b2f(hstash[pn][row*136+g*16+i])*outw_s[g*16+i];
      red[row][g]=s; }
    __syncthreads();
    if(tid<16){ float s=outb_s;
      #pragma unroll
      for(int g=0;g<8;g++) s+=red[tid][g];
      out[(b0+tid)*24+t]=s*scl_s[tid]; }
    p=pn;
  }
}

extern "C" void kernel_launch(void* const* d_in, const int* in_sizes, int n_in,
                              void* d_out, int out_size, void* d_ws, size_t ws_size,
                              hipStream_t stream)
{
  (void)in_sizes; (void)n_in; (void)out_size; (void)ws_size;
  const int*   cat  = (const int*)d_in[0];
  const float* sreal= (const float*)d_in[1];
  const float* ptf  = (const float*)d_in[2];
  const float* tgt  = (const float*)d_in[3];
  const float* obs  = (const float*)d_in[4];
  const float* ftf  = (const float*)d_in[5];
  const float* emb  = (const float*)d_in[6];
  const float* gWih = (const float*)d_in[7];
  const float* gWhh = (const float*)d_in[8];
  const float* gbih = (const float*)d_in[9];
  const float* gbhh = (const float*)d_in[10];
  const float* eWih = (const float*)d_in[11];
  const float* eWhh = (const float*)d_in[12];
  const float* encb = (const float*)d_in[13];
  const float* dWih = (const float*)d_in[14];
  const float* dWhh = (const float*)d_in[15];
  const float* decb = (const float*)d_in[16];
  const float* outW = (const float*)d_in[17];
  const float* outb = (const float*)d_in[18];
  float* ws  = (float*)d_ws;
  float* out = (float*)d_out;

  hipMemsetAsync(d_ws, 0, 2*sizeof(float), stream);
  scale_kernel<<<dim3(8192/256), dim3(256), 0, stream>>>(tgt, obs, ws);
  prep_w<<<dim3(512), dim3(256), 0, stream>>>(gWih,gWhh,eWih,eWhh,dWih,dWhh,ws);
  prep_x<<<dim3(128), dim3(256), 0, stream>>>(tgt, ptf, ftf, ws);
  deepar_main<<<dim3(512), dim3(512), 0, stream>>>(cat,sreal,emb,gbih,gbhh,encb,decb,
                                                   outW,outb,ws,out);
}

// Round 7
// 932.051 us; speedup vs baseline: 1.0217x; 1.0217x over previous
//
#include <hip/hip_runtime.h>
#include <math.h>

typedef short bf16x8 __attribute__((ext_vector_type(8)));
typedef float f32x4 __attribute__((ext_vector_type(4)));
typedef unsigned short u16;
typedef unsigned int u32;

// float-region offsets in ws
#define WSUMS 0
#define TOTWS 1
#define WSUM_OFF 2
#define TOTW_OFF 8194
#define SCL_F 16386
#define WB_BYTE 98432      // start of bf16/u16 region (byte offset)

// u16-region offsets
#define GWI_U 0            // [384][32]   gru Wih (cols 0..29, pad 0)
#define GWH_U 12288        // [384][128]  gru Whh
#define EO_U  61440        // [7][512][256]  enc (Wih|Whh)
#define DO_U  978944       // [512][320]  dec packed
#define XG_U  1142784      // [7][8192][24][16] gru x feats
#define XD_U  23162880     // [8192][24][16]    dec x feats

// exp2 prescale: v_exp_f32 computes 2^x, so fold log2(e) (sigmoid gates) /
// 2*log2(e) (tanh gates) into the weights+biases at prep time.
#define L2E 1.4426950408889634f
#define T2E 2.8853900817779268f

__constant__ int cLAG[8] = {144,120,96,72,48,24,0,168};

// rcp instead of IEEE divide (no -ffast-math in harness): ~1ulp, invisible in bf16.
__device__ __forceinline__ float sig2(float x){   // x already *log2e
  return __builtin_amdgcn_rcpf(1.0f+__builtin_amdgcn_exp2f(-x));
}
__device__ __forceinline__ float th2(float x){    // x already *2log2e
  return __builtin_fmaf(-2.0f, __builtin_amdgcn_rcpf(__builtin_amdgcn_exp2f(x)+1.0f), 1.0f);
}
__device__ __forceinline__ float thc(float x){    // unscaled arg (cell state)
  return th2(x*T2E);
}
__device__ __forceinline__ u16 f2b(float x){ u32 u=__float_as_uint(x); return (u16)((u + 0x7fffu + ((u>>16)&1u))>>16); }
__device__ __forceinline__ float b2f(u16 v){ return __uint_as_float(((u32)v)<<16); }
// packed f32->bf16 (RNE, identical to f2b) - 1 instr for 2 values
__device__ __forceinline__ u32 f2b_pk(float lo, float hi){
  u32 r; asm("v_cvt_pk_bf16_f32 %0, %1, %2" : "=v"(r) : "v"(lo), "v"(hi)); return r;
}
__device__ __forceinline__ void pin(bf16x8 &x){
  f32x4 t = __builtin_bit_cast(f32x4, x);
  asm volatile("" : "+v"(t));
  x = __builtin_bit_cast(bf16x8, t);
}

#define MFMA(a,b,c) __builtin_amdgcn_mfma_f32_16x16x32_bf16(a,b,c,0,0,0)

__global__ void scale_kernel(const float* __restrict__ tgt,
                             const float* __restrict__ obs,
                             float* __restrict__ ws)
{
  __shared__ float s1[256], s2[256];
  int b = blockIdx.x*256 + threadIdx.x;
  float wsum=0.f, totw=0.f;
  const float* tr = tgt + b*336 + 168;
  const float* wr = obs + b*336 + 168;
  for(int t=0;t<168;t++){ float w=wr[t]; wsum += fabsf(tr[t])*w; totw += w; }
  ws[WSUM_OFF + b] = wsum;
  ws[TOTW_OFF + b] = totw;
  s1[threadIdx.x]=wsum; s2[threadIdx.x]=totw;
  __syncthreads();
  for(int s=128;s>0;s>>=1){
    if(threadIdx.x<s){ s1[threadIdx.x]+=s1[threadIdx.x+s]; s2[threadIdx.x]+=s2[threadIdx.x+s]; }
    __syncthreads();
  }
  if(threadIdx.x==0){ atomicAdd(&ws[WSUMS], s1[0]); atomicAdd(&ws[TOTWS], s2[0]); }
}

// Gate rows: [0,128)=r/i sig, [128,256)=z/f sig, [256,384)=n/g tanh, [384,512)=o sig.
// sigmoid rows *L2E, tanh rows *T2E (see sig2/th2).
__global__ void prep_w(const float* __restrict__ gWih, const float* __restrict__ gWhh,
                       const float* __restrict__ eWih, const float* __restrict__ eWhh,
                       const float* __restrict__ dWih, const float* __restrict__ dWhh,
                       float* __restrict__ ws)
{
  u16* WU = (u16*)((char*)ws + WB_BYTE);
  int tid = blockIdx.x*blockDim.x + threadIdx.x;
  int nt = gridDim.x*blockDim.x;
  for(int i=tid;i<12288;i+=nt){ int n=i>>5,k=i&31;
    float s=((n>>7)==2)?T2E:L2E;
    WU[GWI_U+i]=(k<30)?f2b(gWih[n*30+k]*s):(u16)0; }
  for(int i=tid;i<49152;i+=nt){ int n=i>>7,k=i&127;
    float s=((n>>7)==2)?T2E:L2E;
    WU[GWH_U+i]=f2b(gWhh[n*128+k]*s); }
  for(int i=tid;i<917504;i+=nt){
    int s=i>>17,r2=i&131071,n=r2>>8,k=r2&255;
    float sc=((n>>7)==2)?T2E:L2E;
    float v=(k<128)?eWih[(s*512+n)*128+k]:eWhh[(s*512+n)*128+(k-128)];
    WU[EO_U+i]=f2b(v*sc);
  }
  for(int i=tid;i<163840;i+=nt){
    int n=i/320, k=i-n*320; float v;
    float sc=((n>>7)==2)?T2E:L2E;
    if(k<128)       v=dWih[n*180+30+k];
    else if(k<136)  v=dWih[n*180+(k-128)];
    else if(k<140)  v=dWih[n*180+8+(k-136)];
    else if(k<144)  v=dWih[n*180+158+(k-140)];
    else if(k<162)  v=dWih[n*180+12+(k-144)];
    else if(k<180)  v=dWih[n*180+162+(k-162)];
    else if(k<192)  v=0.f;
    else            v=dWhh[n*128+(k-192)];
    WU[DO_U+i]=f2b(v*sc);
  }
}

__global__ void prep_x(const float* __restrict__ tgt, const float* __restrict__ ptf,
                       const float* __restrict__ ftf, float* __restrict__ ws)
{
  __shared__ float inv_l[64];
  u16* WU = (u16*)((char*)ws + WB_BYTE);
  const int tid = threadIdx.x;
  const int b0 = blockIdx.x*64;
  if(tid<64){
    int b=b0+tid;
    float wsumv=ws[WSUM_OFF+b], totw=ws[TOTW_OFF+b];
    float def=ws[WSUMS]/fmaxf(ws[TOTWS],1.f);
    float sc=fmaxf(1e-10f,(wsumv>0.f)?wsumv/fmaxf(totw,1.f):def);
    ws[SCL_F+b]=sc; inv_l[tid]=1.f/sc;
  }
  __syncthreads();
  for(int idx=tid; idx<64*168; idx+=256){
    int bl=idx/168, gt=idx-bl*168; int b=b0+bl;
    float iv=inv_l[bl];
    __align__(16) u16 row[16];
    #pragma unroll
    for(int j=0;j<8;j++) row[j]=f2b(tgt[b*336+cLAG[j]+gt]*iv);
    const float* pp=ptf+((size_t)(b*336+168+gt))*4;
    #pragma unroll
    for(int j=0;j<4;j++) row[8+j]=f2b(pp[j]);
    row[12]=row[13]=row[14]=row[15]=0;
    int seg=gt/24, t=gt-seg*24;
    u16* dst=WU+XG_U+(((size_t)seg*8192+b)*24+t)*16;
    *(uint4*)dst=*(const uint4*)row; *(uint4*)(dst+8)=*(const uint4*)(row+8);
  }
  for(int idx=tid; idx<64*24; idx+=256){
    int bl=idx/24, t=idx-bl*24; int b=b0+bl;
    float iv=inv_l[bl];
    __align__(16) u16 row[16];
    #pragma unroll
    for(int j=0;j<8;j++) row[j]=f2b(tgt[b*336+cLAG[j]+t]*iv);
    #pragma unroll
    for(int j=0;j<4;j++) row[8+j]=f2b(ptf[((size_t)(b*336+168+t))*4+j]);
    #pragma unroll
    for(int j=0;j<4;j++) row[12+j]=f2b(ftf[b*96+t*4+j]);
    u16* dst=WU+XD_U+((size_t)b*24+t)*16;
    *(uint4*)dst=*(const uint4*)row; *(uint4*)(dst+8)=*(const uint4*)(row+8);
  }
}

// beta(r,t) = (t>>2)*64 + r*4 + (t&3): encbuf row index (t-group-major)
// Direct strided A-frag reads from encbuf (row = tb + l15*4) are conflict-free
// (verified R6: conflicts 4.74e7 -> 4.58e7 after switching to direct reads).
// Enc uses DELAYED h-flush: step t reads rows(t) direct post-barrier; the
// encbuf write of h(t-1) (rows t-1, whose readers finished pre-barrier(t))
// happens in step t. No snapshot copy, no pipelined accumulator (R6's accA
// spilled: WRITE_SIZE 768->3747 KB). rows(t) partition is disjoint across t.
// LDS (~136 KB) caps residency at 1 block/CU = 2 waves/EU. The v252-v255 entry
// clobber statically forces a 256-VGPR allocation (the allocator otherwise
// targets 4 waves/EU -> 128 regs -> weight spills, measured r3/r5/r6/r7).
__global__ __launch_bounds__(512,2)
__attribute__((amdgpu_waves_per_eu(2,2)))
void deepar_main(const int* __restrict__ cat, const float* __restrict__ sreal,
                 const float* __restrict__ emb,
                 const float* __restrict__ gbih, const float* __restrict__ gbhh,
                 const float* __restrict__ encb, const float* __restrict__ decb,
                 const float* __restrict__ outW, const float* __restrict__ outb,
                 float* __restrict__ ws, float* __restrict__ out)
{
  asm volatile("" ::: "v252","v253","v254","v255");   // force 256-VGPR allocation

  const u16* __restrict__ WU=(const u16*)((const char*)ws+WB_BYTE);

  __shared__ __align__(16) u16 encbuf[384*136];   // enc_out / hv, in place (beta rows)
  __shared__ __align__(16) u16 Xast[4][64*40];    // GRU x tile, depth-2 prefetch ring
  __shared__ __align__(16) u16 Xdast[2][16*72];   // dec extra feats, double-buffered
  __shared__ __align__(16) u16 hstash[2][16*136]; // recurrent h, double-buffered
  __shared__ u16 statb[16][18];
  __shared__ float scl_s[16];
  __shared__ float outw_s[128];
  __shared__ float red[16][8];
  __shared__ float outb_s;

  const int tid=threadIdx.x;
  const int b0=blockIdx.x*16;
  const int wv=tid>>6, lane=tid&63, quad=lane>>4, l15=lane&15;

  // GRU x-tile stage for global chunk gc into Xast[gc&3], issued 2 chunks ahead:
  // buffer (gc+2)&3 was last READ by compute(gc-2); barriers (gc-2),(gc-1)
  // separate -> race-free. Depth 2 gives ~2 chunks (~2000cy) to cover HBM latency.
  auto stageX = [&](int gc){
    if(tid<128 && gc<42){
      int sg=gc/6, cc=gc-sg*6;
      int a=tid>>1;
      u16* Xb=&Xast[gc&3][0];
      const u16* src=WU+XG_U+(((size_t)sg*8192+b0+(a>>2))*24+4*cc+(a&3))*16;
      if(tid&1) *(uint2*)(Xb+a*40+8)=*(const uint2*)(src+8);
      else      *(uint4*)(Xb+a*40)  =*(const uint4*)src;
    }
  };

  if(tid<16) scl_s[tid]=ws[SCL_F+b0+tid];
  if(tid<128) outw_s[tid]=outW[tid];
  if(tid==128) outb_s=outb[0];
  if(tid>=256){ int q=tid-256; int r=q>>4,k=q&15; statb[r][k]=f2b(emb[cat[b0+r]*16+k]); }
  { const uint4 z4={0,0,0,0};
    for(int i=tid;i<6528;i+=512) *(uint4*)(encbuf+i*8)=z4;        // 6528*8 = 384*136
    for(int i=tid;i<544;i+=512)  *(uint4*)(&hstash[0][0]+i*8)=z4; // 544*8 = 2*16*136
  }
  __syncthreads();
  if(tid<16){ statb[tid][16]=f2b(sreal[b0+tid]); statb[tid][17]=f2b(logf(scl_s[tid])); }
  __syncthreads();
  // prebuild t-invariant columns of GRU / dec A-tiles (all ring buffers)
  for(int i=tid;i<1280;i+=512){ int a=i/20, k=i-a*20+12;
    u16 v=(k<30)?statb[a>>2][k-12]:(u16)0;
    Xast[0][a*40+k]=v; Xast[1][a*40+k]=v; Xast[2][a*40+k]=v; Xast[3][a*40+k]=v; }
  for(int i=tid;i<896;i+=512){ int rr=i/56, k=i-rr*56+16;
    u16 v; if(k<34) v=statb[rr][k-16]; else if(k<52) v=statb[rr][k-34]; else v=0;
    Xdast[0][rr*72+k]=v; Xdast[1][rr*72+k]=v; }
  stageX(0); stageX(1);   // prologue prefetch (cols 0-11, disjoint from prebuild 12-31)
  __syncthreads();

  float gbi[3], gbh[3];
  #pragma unroll
  for(int j=0;j<3;j++){ int nb=(wv+j*8)*16+l15;
    float s=(j==2)?T2E:L2E;
    gbi[j]=gbih[nb]*s; gbh[j]=gbhh[nb]*s; }
  // r/z gates only ever consumed as (ih+hh): merged bias. Bias f32x4 vectors
  // seed the FIRST MFMA's C operand -> no per-chunk accumulator-init movs.
  const float gbr=gbi[0]+gbh[0], gbz=gbi[1]+gbh[1];
  const f32x4 b4r ={gbr,gbr,gbr,gbr};
  const f32x4 b4z ={gbz,gbz,gbz,gbz};
  const f32x4 b4i2={gbi[2],gbi[2],gbi[2],gbi[2]};
  const f32x4 b4h2={gbh[2],gbh[2],gbh[2],gbh[2]};

  float cst[4]={0.f,0.f,0.f,0.f};
  const int hc=wv*16+l15;
  int p=0;                                  // hstash parity

  for(int seg=0;seg<7;seg++){
    // ---- GRU weights: load + pin (live this phase only) ----
    bf16x8 gwi[3]; bf16x8 gwh[3][4];
    #pragma unroll
    for(int j=0;j<3;j++){
      int nb=(wv+j*8)*16+l15;
      gwi[j]=*(const bf16x8*)(WU+GWI_U+nb*32+quad*8); pin(gwi[j]);
      #pragma unroll
      for(int kt=0;kt<4;kt++){ gwh[j][kt]=*(const bf16x8*)(WU+GWH_U+nb*128+kt*32+quad*8); pin(gwh[j][kt]); }
    }

    // ============ GRU: 6 chunks x 64 A-rows, in place, 1 barrier/chunk ============
    for(int c=0;c<6;c++){
      stageX(seg*6+c+2);                    // prefetch 2 chunks ahead
      const u16* Xb = &Xast[(seg*6+c)&3][0];

      f32x4 g01[2][4], a2[4], h2[4];
      #pragma unroll
      for(int mt=0;mt<4;mt++){
        bf16x8 af=*(const bf16x8*)(Xb+(mt*16+l15)*40+quad*8);
        g01[0][mt]=MFMA(af,gwi[0],b4r);
        g01[1][mt]=MFMA(af,gwi[1],b4z);
        a2[mt]   =MFMA(af,gwi[2],b4i2);
      }
      const u16* ebase=encbuf+(size_t)(c*64)*136;
      #pragma unroll
      for(int kt=0;kt<4;kt++)
        #pragma unroll
        for(int mt=0;mt<4;mt++){
          bf16x8 af=*(const bf16x8*)(ebase+(mt*16+l15)*136+kt*32+quad*8);
          g01[0][mt]=MFMA(af,gwh[0][kt],g01[0][mt]);
          g01[1][mt]=MFMA(af,gwh[1][kt],g01[1][mt]);
          h2[mt]   =MFMA(af,gwh[2][kt],(kt==0)?b4h2:h2[mt]);
        }
      u16 hv16[4][4];
      #pragma unroll
      for(int mt=0;mt<4;mt++){
        float hv[4];
        #pragma unroll
        for(int reg=0;reg<4;reg++){
          int a=mt*16+quad*4+reg;
          float rg=sig2(g01[0][mt][reg]);
          float zg=sig2(g01[1][mt][reg]);
          float hp=b2f(encbuf[(c*64+a)*136+hc]);
          float nn=th2(__builtin_fmaf(rg,h2[mt][reg],a2[mt][reg]));
          hv[reg]=__builtin_fmaf(zg,hp-nn,nn);
        }
        u32 p01=f2b_pk(hv[0],hv[1]), p23=f2b_pk(hv[2],hv[3]);
        hv16[mt][0]=(u16)p01; hv16[mt][1]=(u16)(p01>>16);
        hv16[mt][2]=(u16)p23; hv16[mt][3]=(u16)(p23>>16);
      }
      __syncthreads();   // all reads of rows c done before in-place overwrite
      #pragma unroll
      for(int mt=0;mt<4;mt++)
        #pragma unroll
        for(int reg=0;reg<4;reg++)
          encbuf[(c*64+mt*16+quad*4+reg)*136+hc]=hv16[mt][reg];
    }

    // ===== encoder LSTM: resident weights, 24 steps, delayed h-flush =====
    bf16x8 we[4][8]; f32x4 b4e[4];
    #pragma unroll
    for(int j=0;j<4;j++){
      int nb=(wv+j*8)*16+l15;
      float b=encb[seg*512+nb]*((j==2)?T2E:L2E);
      b4e[j]=(f32x4){b,b,b,b};
      #pragma unroll
      for(int kt=0;kt<8;kt++){
        we[j][kt]=*(const bf16x8*)(WU+EO_U+(size_t)seg*131072+nb*256+kt*32+quad*8);
        pin(we[j][kt]);
      }
    }
    u16 hprev[4]; int tbprev=0;
    for(int t=0;t<24;t++){
      int tb=(t>>2)*64+(t&3);
      __syncthreads();                       // h(t-1) visible; step(t-1) A-reads done
      const u16* Hb=&hstash[p][0];
      const u16* Ar=encbuf+(size_t)(tb+l15*4)*136;  // rows(t): pristine hv, written only by step t
      f32x4 acc[4];
      #pragma unroll
      for(int kt=0;kt<8;kt++){
        bf16x8 af=(kt<4)? *(const bf16x8*)(Ar+kt*32+quad*8)
                        : *(const bf16x8*)(Hb+l15*136+(kt-4)*32+quad*8);
        #pragma unroll
        for(int j=0;j<4;j++) acc[j]=MFMA(af,we[j][kt],(kt==0)?b4e[j]:acc[j]);
      }
      if(t>0){  // delayed flush of h(t-1) -> rows(t-1); readers finished pre-barrier(t)
        #pragma unroll
        for(int reg=0;reg<4;reg++)
          encbuf[(tbprev+(quad*4+reg)*4)*136+hc]=hprev[reg];
      }
      { float hf[4];
        #pragma unroll
        for(int reg=0;reg<4;reg++){
          float ig=sig2(acc[0][reg]),fg=sig2(acc[1][reg]);
          float gg=th2(acc[2][reg]), og=sig2(acc[3][reg]);
          float c_=__builtin_fmaf(fg,cst[reg],ig*gg); cst[reg]=c_;
          hf[reg]=og*thc(c_);
        }
        u32 p01=f2b_pk(hf[0],hf[1]), p23=f2b_pk(hf[2],hf[3]);
        hprev[0]=(u16)p01; hprev[1]=(u16)(p01>>16);
        hprev[2]=(u16)p23; hprev[3]=(u16)(p23>>16);
      }
      int pn=p^1;
      u16* Hw=&hstash[pn][0];
      #pragma unroll
      for(int reg=0;reg<4;reg++)
        Hw[(quad*4+reg)*136+hc]=hprev[reg];  // opposite buffer: no read hazard
      tbprev=tb; p=pn;
    }
    // epilogue flush of h(23) -> rows(23); next reader (GRU chunk 5 / dec) is >=5 barriers away
    #pragma unroll
    for(int reg=0;reg<4;reg++)
      encbuf[(tbprev+(quad*4+reg)*4)*136+hc]=hprev[reg];
  }

  // ================= decoder LSTM + projection =================
  bf16x8 wd[4][10]; f32x4 b4d[4];
  #pragma unroll
  for(int j=0;j<4;j++){
    int nb=(wv+j*8)*16+l15;
    float b=decb[nb]*((j==2)?T2E:L2E);
    b4d[j]=(f32x4){b,b,b,b};
    #pragma unroll
    for(int kt=0;kt<10;kt++){
      wd[j][kt]=*(const bf16x8*)(WU+DO_U+nb*320+kt*32+quad*8);
      pin(wd[j][kt]);
    }
  }
  // prologue: stage Xd(0); barrier also publishes enc's final h-flush
  if(tid>=256 && tid<288){ int q=tid-256; int rr=q>>1;
    const u16* src=WU+XD_U+((size_t)(b0+rr)*24+0)*16;
    u16* Xw=&Xdast[0][0];
    if(q&1) *(uint4*)(Xw+rr*72+8)=*(const uint4*)(src+8);
    else    *(uint4*)(Xw+rr*72)  =*(const uint4*)src; }
  __syncthreads();
  for(int t=0;t<24;t++){
    int tb=(t>>2)*64+(t&3);
    const u16* Ar=encbuf+(size_t)(tb+l15*4)*136;   // read-only in dec: no ordering needed
    const u16* Xd=&Xdast[t&1][0];
    const u16* Hb=&hstash[p][0];
    f32x4 acc[4];
    #pragma unroll
    for(int kt=0;kt<10;kt++){
      bf16x8 af=(kt<4)? *(const bf16x8*)(Ar+kt*32+quad*8)
              :(kt<6)? *(const bf16x8*)(Xd+l15*72+(kt-4)*32+quad*8)
                     : *(const bf16x8*)(Hb+l15*136+(kt-6)*32+quad*8);
      #pragma unroll
      for(int j=0;j<4;j++) acc[j]=MFMA(af,wd[j][kt],(kt==0)?b4d[j]:acc[j]);
    }
    // prefetch Xd(t+1) into opposite buffer: last reader was MFMA(t-1),
    // two barriers back -> race-free
    if(t<23 && tid>=256 && tid<288){ int q=tid-256; int rr=q>>1;
      const u16* src=WU+XD_U+((size_t)(b0+rr)*24+t+1)*16;
      u16* Xw=&Xdast[(t+1)&1][0];
      if(q&1) *(uint4*)(Xw+rr*72+8)=*(const uint4*)(src+8);
      else    *(uint4*)(Xw+rr*72)  =*(const uint4*)src; }
    u16 hnew[4];
    { float hf[4];
      #pragma unroll
      for(int reg=0;reg<4;reg++){
        float ig=sig2(acc[0][reg]),fg=sig2(acc[1][reg]);
        float gg=th2(acc[2][reg]), og=sig2(acc[3][reg]);
        float c_=__builtin_fmaf(fg,cst[reg],ig*gg); cst[reg]=c_;
        hf[reg]=og*thc(c_);
      }
      u32 p01=f2b_pk(hf[0],hf[1]), p23=f2b_pk(hf[2],hf[3]);
      hnew[0]=(u16)p01; hnew[1]=(u16)(p01>>16);
      hnew[2]=(u16)p23; hnew[3]=(u16)(p23>>16);
    }
    int pn=p^1;
    #pragma unroll
    for(int reg=0;reg<4;reg++)
      hstash[pn][(quad*4+reg)*136+hc]=hnew[reg];
    __syncthreads();      // projection needs the full new h row (+ Xd stage done)
    if(tid<128){ int row=tid>>3,g=tid&7; float s=0.f;
      #pragma unroll
      for(int i=0;i<16;i++) s+=b2f(hstash[pn][row*136+g*16+i])*outw_s[g*16+i];
      red[row][g]=s; }
    __syncthreads();
    if(tid<16){ float s=outb_s;
      #pragma unroll
      for(int g=0;g<8;g++) s+=red[tid][g];
      out[(b0+tid)*24+t]=s*scl_s[tid]; }
    p=pn;
  }
}

extern "C" void kernel_launch(void* const* d_in, const int* in_sizes, int n_in,
                              void* d_out, int out_size, void* d_ws, size_t ws_size,
                              hipStream_t stream)
{
  (void)in_sizes; (void)n_in; (void)out_size; (void)ws_size;
  const int*   cat  = (const int*)d_in[0];
  const float* sreal= (const float*)d_in[1];
  const float* ptf  = (const float*)d_in[2];
  const float* tgt  = (const float*)d_in[3];
  const float* obs  = (const float*)d_in[4];
  const float* ftf  = (const float*)d_in[5];
  const float* emb  = (const float*)d_in[6];
  const float* gWih = (const float*)d_in[7];
  const float* gWhh = (const float*)d_in[8];
  const float* gbih = (const float*)d_in[9];
  const float* gbhh = (const float*)d_in[10];
  const float* eWih = (const float*)d_in[11];
  const float* eWhh = (const float*)d_in[12];
  const float* encb = (const float*)d_in[13];
  const float* dWih = (const float*)d_in[14];
  const float* dWhh = (const float*)d_in[15];
  const float* decb = (const float*)d_in[16];
  const float* outW = (const float*)d_in[17];
  const float* outb = (const float*)d_in[18];
  float* ws  = (float*)d_ws;
  float* out = (float*)d_out;

  hipMemsetAsync(d_ws, 0, 2*sizeof(float), stream);
  scale_kernel<<<dim3(8192/256), dim3(256), 0, stream>>>(tgt, obs, ws);
  prep_w<<<dim3(512), dim3(256), 0, stream>>>(gWih,gWhh,eWih,eWhh,dWih,dWhh,ws);
  prep_x<<<dim3(128), dim3(256), 0, stream>>>(tgt, ptf, ftf, ws);
  deepar_main<<<dim3(512), dim3(512), 0, stream>>>(cat,sreal,emb,gbih,gbhh,encb,decb,
                                                   outW,outb,ws,out);
}

// Round 8
// 897.327 us; speedup vs baseline: 1.0612x; 1.0387x over previous
//
#include <hip/hip_runtime.h>
#include <math.h>

typedef short bf16x8 __attribute__((ext_vector_type(8)));
typedef float f32x4 __attribute__((ext_vector_type(4)));
typedef unsigned short u16;
typedef unsigned int u32;

// float-region offsets in ws
#define WSUMS 0
#define TOTWS 1
#define WSUM_OFF 2
#define TOTW_OFF 8194
#define SCL_F 16386
#define WB_BYTE 98432      // start of bf16/u16 region (byte offset)

// u16-region offsets
#define GWI_U 0            // [384][32]   gru Wih (cols 0..29, pad 0)
#define GWH_U 12288        // [384][128]  gru Whh
#define EO_U  61440        // [7][512][256]  enc (Wih|Whh)
#define DO_U  978944       // [512][320]  dec packed
#define XG_U  1142784      // [7][8192][24][16] gru x feats
#define XD_U  23162880     // [8192][24][16]    dec x feats

// exp2 prescale: v_exp_f32 computes 2^x, so fold log2(e) (sigmoid gates) /
// 2*log2(e) (tanh gates) into the weights+biases at prep time.
#define L2E 1.4426950408889634f
#define T2E 2.8853900817779268f

__constant__ int cLAG[8] = {144,120,96,72,48,24,0,168};

// rcp instead of IEEE divide (no -ffast-math in harness): ~1ulp, invisible in bf16.
__device__ __forceinline__ float sig2(float x){   // x already *log2e
  return __builtin_amdgcn_rcpf(1.0f+__builtin_amdgcn_exp2f(-x));
}
__device__ __forceinline__ float th2(float x){    // x already *2log2e
  return __builtin_fmaf(-2.0f, __builtin_amdgcn_rcpf(__builtin_amdgcn_exp2f(x)+1.0f), 1.0f);
}
__device__ __forceinline__ float thc(float x){    // unscaled arg (cell state)
  return th2(x*T2E);
}
__device__ __forceinline__ u16 f2b(float x){ u32 u=__float_as_uint(x); return (u16)((u + 0x7fffu + ((u>>16)&1u))>>16); }
__device__ __forceinline__ float b2f(u16 v){ return __uint_as_float(((u32)v)<<16); }
// packed f32->bf16 (RNE, identical to f2b) - 1 instr for 2 values
__device__ __forceinline__ u32 f2b_pk(float lo, float hi){
  u32 r; asm("v_cvt_pk_bf16_f32 %0, %1, %2" : "=v"(r) : "v"(lo), "v"(hi)); return r;
}
__device__ __forceinline__ void pin(bf16x8 &x){
  f32x4 t = __builtin_bit_cast(f32x4, x);
  asm volatile("" : "+v"(t));
  x = __builtin_bit_cast(bf16x8, t);
}

#define MFMA(a,b,c) __builtin_amdgcn_mfma_f32_16x16x32_bf16(a,b,c,0,0,0)

__global__ void scale_kernel(const float* __restrict__ tgt,
                             const float* __restrict__ obs,
                             float* __restrict__ ws)
{
  __shared__ float s1[256], s2[256];
  int b = blockIdx.x*256 + threadIdx.x;
  float wsum=0.f, totw=0.f;
  const float* tr = tgt + b*336 + 168;
  const float* wr = obs + b*336 + 168;
  for(int t=0;t<168;t++){ float w=wr[t]; wsum += fabsf(tr[t])*w; totw += w; }
  ws[WSUM_OFF + b] = wsum;
  ws[TOTW_OFF + b] = totw;
  s1[threadIdx.x]=wsum; s2[threadIdx.x]=totw;
  __syncthreads();
  for(int s=128;s>0;s>>=1){
    if(threadIdx.x<s){ s1[threadIdx.x]+=s1[threadIdx.x+s]; s2[threadIdx.x]+=s2[threadIdx.x+s]; }
    __syncthreads();
  }
  if(threadIdx.x==0){ atomicAdd(&ws[WSUMS], s1[0]); atomicAdd(&ws[TOTWS], s2[0]); }
}

// Gate rows: [0,128)=r/i sig, [128,256)=z/f sig, [256,384)=n/g tanh, [384,512)=o sig.
// sigmoid rows *L2E, tanh rows *T2E (see sig2/th2).
__global__ void prep_w(const float* __restrict__ gWih, const float* __restrict__ gWhh,
                       const float* __restrict__ eWih, const float* __restrict__ eWhh,
                       const float* __restrict__ dWih, const float* __restrict__ dWhh,
                       float* __restrict__ ws)
{
  u16* WU = (u16*)((char*)ws + WB_BYTE);
  int tid = blockIdx.x*blockDim.x + threadIdx.x;
  int nt = gridDim.x*blockDim.x;
  for(int i=tid;i<12288;i+=nt){ int n=i>>5,k=i&31;
    float s=((n>>7)==2)?T2E:L2E;
    WU[GWI_U+i]=(k<30)?f2b(gWih[n*30+k]*s):(u16)0; }
  for(int i=tid;i<49152;i+=nt){ int n=i>>7,k=i&127;
    float s=((n>>7)==2)?T2E:L2E;
    WU[GWH_U+i]=f2b(gWhh[n*128+k]*s); }
  for(int i=tid;i<917504;i+=nt){
    int s=i>>17,r2=i&131071,n=r2>>8,k=r2&255;
    float sc=((n>>7)==2)?T2E:L2E;
    float v=(k<128)?eWih[(s*512+n)*128+k]:eWhh[(s*512+n)*128+(k-128)];
    WU[EO_U+i]=f2b(v*sc);
  }
  for(int i=tid;i<163840;i+=nt){
    int n=i/320, k=i-n*320; float v;
    float sc=((n>>7)==2)?T2E:L2E;
    if(k<128)       v=dWih[n*180+30+k];
    else if(k<136)  v=dWih[n*180+(k-128)];
    else if(k<140)  v=dWih[n*180+8+(k-136)];
    else if(k<144)  v=dWih[n*180+158+(k-140)];
    else if(k<162)  v=dWih[n*180+12+(k-144)];
    else if(k<180)  v=dWih[n*180+162+(k-162)];
    else if(k<192)  v=0.f;
    else            v=dWhh[n*128+(k-192)];
    WU[DO_U+i]=f2b(v*sc);
  }
}

__global__ void prep_x(const float* __restrict__ tgt, const float* __restrict__ ptf,
                       const float* __restrict__ ftf, float* __restrict__ ws)
{
  __shared__ float inv_l[64];
  u16* WU = (u16*)((char*)ws + WB_BYTE);
  const int tid = threadIdx.x;
  const int b0 = blockIdx.x*64;
  if(tid<64){
    int b=b0+tid;
    float wsumv=ws[WSUM_OFF+b], totw=ws[TOTW_OFF+b];
    float def=ws[WSUMS]/fmaxf(ws[TOTWS],1.f);
    float sc=fmaxf(1e-10f,(wsumv>0.f)?wsumv/fmaxf(totw,1.f):def);
    ws[SCL_F+b]=sc; inv_l[tid]=1.f/sc;
  }
  __syncthreads();
  for(int idx=tid; idx<64*168; idx+=256){
    int bl=idx/168, gt=idx-bl*168; int b=b0+bl;
    float iv=inv_l[bl];
    __align__(16) u16 row[16];
    #pragma unroll
    for(int j=0;j<8;j++) row[j]=f2b(tgt[b*336+cLAG[j]+gt]*iv);
    const float* pp=ptf+((size_t)(b*336+168+gt))*4;
    #pragma unroll
    for(int j=0;j<4;j++) row[8+j]=f2b(pp[j]);
    row[12]=row[13]=row[14]=row[15]=0;
    int seg=gt/24, t=gt-seg*24;
    u16* dst=WU+XG_U+(((size_t)seg*8192+b)*24+t)*16;
    *(uint4*)dst=*(const uint4*)row; *(uint4*)(dst+8)=*(const uint4*)(row+8);
  }
  for(int idx=tid; idx<64*24; idx+=256){
    int bl=idx/24, t=idx-bl*24; int b=b0+bl;
    float iv=inv_l[bl];
    __align__(16) u16 row[16];
    #pragma unroll
    for(int j=0;j<8;j++) row[j]=f2b(tgt[b*336+cLAG[j]+t]*iv);
    #pragma unroll
    for(int j=0;j<4;j++) row[8+j]=f2b(ptf[((size_t)(b*336+168+t))*4+j]);
    #pragma unroll
    for(int j=0;j<4;j++) row[12+j]=f2b(ftf[b*96+t*4+j]);
    u16* dst=WU+XD_U+((size_t)b*24+t)*16;
    *(uint4*)dst=*(const uint4*)row; *(uint4*)(dst+8)=*(const uint4*)(row+8);
  }
}

// beta(r,t) = (t>>2)*64 + r*4 + (t&3): encbuf row index (t-group-major)
// TRANSPOSED MFMA OUTPUT (this round): D = MFMA(W_frag, x_frag, C) computes
// (x W^T)^T -- lane owns (batch=l15, channels=quad*4+reg, 4 CONSECUTIVE u16).
// h-writes become one b64 (was 4 scattered b16 at an unavoidable 8-way bank
// alias: quad spacing 16 rows x 16B-aligned stride == 0 mod 32 banks). A/B
// frag layouts are symmetric so the SAME weight registers serve as A-operand.
// Same k-order + C-chaining -> bit-identical math. cst ownership re-keyed
// (batch l15, channel wv*16+quad*4+reg) consistently across GRU/enc/dec.
// Delayed h-flush as R7 (step t reads rows(t), flushes h(t-1) to rows(t-1)).
// LDS (~136 KB) caps residency at 1 block/CU = 2 waves/EU. The v252-v255 entry
// clobber statically forces a 256-VGPR allocation (the allocator otherwise
// targets 4 waves/EU -> 128 regs -> weight spills, measured r3/r5/r6/r7).
__global__ __launch_bounds__(512,2)
__attribute__((amdgpu_waves_per_eu(2,2)))
void deepar_main(const int* __restrict__ cat, const float* __restrict__ sreal,
                 const float* __restrict__ emb,
                 const float* __restrict__ gbih, const float* __restrict__ gbhh,
                 const float* __restrict__ encb, const float* __restrict__ decb,
                 const float* __restrict__ outW, const float* __restrict__ outb,
                 float* __restrict__ ws, float* __restrict__ out)
{
  asm volatile("" ::: "v252","v253","v254","v255");   // force 256-VGPR allocation

  const u16* __restrict__ WU=(const u16*)((const char*)ws+WB_BYTE);

  __shared__ __align__(16) u16 encbuf[384*136];   // enc_out / hv, in place (beta rows)
  __shared__ __align__(16) u16 Xast[4][64*40];    // GRU x tile, depth-2 prefetch ring
  __shared__ __align__(16) u16 Xdast[2][16*72];   // dec extra feats, double-buffered
  __shared__ __align__(16) u16 hstash[2][16*136]; // recurrent h, double-buffered
  __shared__ u16 statb[16][18];
  __shared__ float scl_s[16];
  __shared__ float outw_s[128];
  __shared__ float red[16][8];
  __shared__ float outb_s;

  const int tid=threadIdx.x;
  const int b0=blockIdx.x*16;
  const int wv=tid>>6, lane=tid&63, quad=lane>>4, l15=lane&15;
  const int ccol=wv*16+quad*4;   // this thread's 4-channel column base

  // GRU x-tile stage for global chunk gc into Xast[gc&3], issued 2 chunks ahead:
  // buffer (gc+2)&3 was last READ by compute(gc-2); barriers (gc-2),(gc-1)
  // separate -> race-free. Depth 2 gives ~2 chunks (~2000cy) to cover HBM latency.
  auto stageX = [&](int gc){
    if(tid<128 && gc<42){
      int sg=gc/6, cc=gc-sg*6;
      int a=tid>>1;
      u16* Xb=&Xast[gc&3][0];
      const u16* src=WU+XG_U+(((size_t)sg*8192+b0+(a>>2))*24+4*cc+(a&3))*16;
      if(tid&1) *(uint2*)(Xb+a*40+8)=*(const uint2*)(src+8);
      else      *(uint4*)(Xb+a*40)  =*(const uint4*)src;
    }
  };

  if(tid<16) scl_s[tid]=ws[SCL_F+b0+tid];
  if(tid<128) outw_s[tid]=outW[tid];
  if(tid==128) outb_s=outb[0];
  if(tid>=256){ int q=tid-256; int r=q>>4,k=q&15; statb[r][k]=f2b(emb[cat[b0+r]*16+k]); }
  { const uint4 z4={0,0,0,0};
    for(int i=tid;i<6528;i+=512) *(uint4*)(encbuf+i*8)=z4;        // 6528*8 = 384*136
    for(int i=tid;i<544;i+=512)  *(uint4*)(&hstash[0][0]+i*8)=z4; // 544*8 = 2*16*136
  }
  __syncthreads();
  if(tid<16){ statb[tid][16]=f2b(sreal[b0+tid]); statb[tid][17]=f2b(logf(scl_s[tid])); }
  __syncthreads();
  // prebuild t-invariant columns of GRU / dec A-tiles (all ring buffers)
  for(int i=tid;i<1280;i+=512){ int a=i/20, k=i-a*20+12;
    u16 v=(k<30)?statb[a>>2][k-12]:(u16)0;
    Xast[0][a*40+k]=v; Xast[1][a*40+k]=v; Xast[2][a*40+k]=v; Xast[3][a*40+k]=v; }
  for(int i=tid;i<896;i+=512){ int rr=i/56, k=i-rr*56+16;
    u16 v; if(k<34) v=statb[rr][k-16]; else if(k<52) v=statb[rr][k-34]; else v=0;
    Xdast[0][rr*72+k]=v; Xdast[1][rr*72+k]=v; }
  stageX(0); stageX(1);   // prologue prefetch (cols 0-11, disjoint from prebuild 12-31)
  __syncthreads();

  // GRU biases, per-reg channels (ccol..ccol+3); r/z merged (ih+hh), n split.
  f32x4 b4r, b4z, b4i2, b4h2;
  {
    float4 bi0=*(const float4*)(gbih+(wv    )*16+quad*4);
    float4 bh0=*(const float4*)(gbhh+(wv    )*16+quad*4);
    float4 bi1=*(const float4*)(gbih+(wv+ 8)*16+quad*4);
    float4 bh1=*(const float4*)(gbhh+(wv+ 8)*16+quad*4);
    float4 bi2=*(const float4*)(gbih+(wv+16)*16+quad*4);
    float4 bh2=*(const float4*)(gbhh+(wv+16)*16+quad*4);
    b4r =(f32x4){(bi0.x+bh0.x)*L2E,(bi0.y+bh0.y)*L2E,(bi0.z+bh0.z)*L2E,(bi0.w+bh0.w)*L2E};
    b4z =(f32x4){(bi1.x+bh1.x)*L2E,(bi1.y+bh1.y)*L2E,(bi1.z+bh1.z)*L2E,(bi1.w+bh1.w)*L2E};
    b4i2=(f32x4){bi2.x*T2E,bi2.y*T2E,bi2.z*T2E,bi2.w*T2E};
    b4h2=(f32x4){bh2.x*T2E,bh2.y*T2E,bh2.z*T2E,bh2.w*T2E};
  }

  float cst[4]={0.f,0.f,0.f,0.f};   // cell state: (batch l15, channel ccol+reg)
  int p=0;                          // hstash parity

  for(int seg=0;seg<7;seg++){
    // ---- GRU weights: load + pin (live this phase only) ----
    bf16x8 gwi[3]; bf16x8 gwh[3][4];
    #pragma unroll
    for(int j=0;j<3;j++){
      int nb=(wv+j*8)*16+l15;
      gwi[j]=*(const bf16x8*)(WU+GWI_U+nb*32+quad*8); pin(gwi[j]);
      #pragma unroll
      for(int kt=0;kt<4;kt++){ gwh[j][kt]=*(const bf16x8*)(WU+GWH_U+nb*128+kt*32+quad*8); pin(gwh[j][kt]); }
    }

    // ============ GRU: 6 chunks x 64 A-rows, in place, 1 barrier/chunk ============
    for(int c=0;c<6;c++){
      stageX(seg*6+c+2);                    // prefetch 2 chunks ahead
      const u16* Xb = &Xast[(seg*6+c)&3][0];

      f32x4 g01[2][4], a2[4], h2[4];
      #pragma unroll
      for(int mt=0;mt<4;mt++){
        bf16x8 af=*(const bf16x8*)(Xb+(mt*16+l15)*40+quad*8);
        g01[0][mt]=MFMA(gwi[0],af,b4r);
        g01[1][mt]=MFMA(gwi[1],af,b4z);
        a2[mt]   =MFMA(gwi[2],af,b4i2);
      }
      const u16* ebase=encbuf+(size_t)(c*64)*136;
      #pragma unroll
      for(int kt=0;kt<4;kt++)
        #pragma unroll
        for(int mt=0;mt<4;mt++){
          bf16x8 af=*(const bf16x8*)(ebase+(mt*16+l15)*136+kt*32+quad*8);
          g01[0][mt]=MFMA(gwh[0][kt],af,g01[0][mt]);
          g01[1][mt]=MFMA(gwh[1][kt],af,g01[1][mt]);
          h2[mt]   =MFMA(gwh[2][kt],af,(kt==0)?b4h2:h2[mt]);
        }
      uint2 hv2[4];
      #pragma unroll
      for(int mt=0;mt<4;mt++){
        uint2 hp2=*(const uint2*)(ebase+(size_t)(mt*16+l15)*136+ccol);  // old h, 4 ch
        float hv[4];
        #pragma unroll
        for(int reg=0;reg<4;reg++){
          float rg=sig2(g01[0][mt][reg]);
          float zg=sig2(g01[1][mt][reg]);
          u32 w=(reg&2)?hp2.y:hp2.x;
          float hp=b2f((u16)((reg&1)?(w>>16):w));
          float nn=th2(__builtin_fmaf(rg,h2[mt][reg],a2[mt][reg]));
          hv[reg]=__builtin_fmaf(zg,hp-nn,nn);
        }
        hv2[mt].x=f2b_pk(hv[0],hv[1]);
        hv2[mt].y=f2b_pk(hv[2],hv[3]);
      }
      __syncthreads();   // all reads of rows c done before in-place overwrite
      #pragma unroll
      for(int mt=0;mt<4;mt++)
        *(uint2*)(encbuf+(size_t)(c*64+mt*16+l15)*136+ccol)=hv2[mt];
    }

    // ===== encoder LSTM: resident weights, 24 steps, delayed h-flush =====
    bf16x8 we[4][8]; f32x4 b4e[4];
    #pragma unroll
    for(int j=0;j<4;j++){
      float s=(j==2)?T2E:L2E;
      float4 bb=*(const float4*)(encb+seg*512+(wv+j*8)*16+quad*4);
      b4e[j]=(f32x4){bb.x*s,bb.y*s,bb.z*s,bb.w*s};
      int nb=(wv+j*8)*16+l15;
      #pragma unroll
      for(int kt=0;kt<8;kt++){
        we[j][kt]=*(const bf16x8*)(WU+EO_U+(size_t)seg*131072+nb*256+kt*32+quad*8);
        pin(we[j][kt]);
      }
    }
    uint2 hprev2={0,0}; int tbprev=0;
    for(int t=0;t<24;t++){
      int tb=(t>>2)*64+(t&3);
      __syncthreads();                       // h(t-1) visible; step(t-1) A-reads done
      const u16* Hb=&hstash[p][0];
      const u16* Ar=encbuf+(size_t)(tb+l15*4)*136;  // rows(t): pristine hv, written only by step t
      f32x4 acc[4];
      #pragma unroll
      for(int kt=0;kt<8;kt++){
        bf16x8 af=(kt<4)? *(const bf16x8*)(Ar+kt*32+quad*8)
                        : *(const bf16x8*)(Hb+l15*136+(kt-4)*32+quad*8);
        #pragma unroll
        for(int j=0;j<4;j++) acc[j]=MFMA(we[j][kt],af,(kt==0)?b4e[j]:acc[j]);
      }
      if(t>0)  // delayed flush of h(t-1) -> rows(t-1); readers finished pre-barrier(t)
        *(uint2*)(encbuf+(size_t)(tbprev+l15*4)*136+ccol)=hprev2;
      { float hf[4];
        #pragma unroll
        for(int reg=0;reg<4;reg++){
          float ig=sig2(acc[0][reg]),fg=sig2(acc[1][reg]);
          float gg=th2(acc[2][reg]), og=sig2(acc[3][reg]);
          float c_=__builtin_fmaf(fg,cst[reg],ig*gg); cst[reg]=c_;
          hf[reg]=og*thc(c_);
        }
        hprev2.x=f2b_pk(hf[0],hf[1]);
        hprev2.y=f2b_pk(hf[2],hf[3]);
      }
      int pn=p^1;
      *(uint2*)(&hstash[pn][0]+(size_t)l15*136+ccol)=hprev2;  // opposite buffer
      tbprev=tb; p=pn;
    }
    // epilogue flush of h(23) -> rows(23); next reader (GRU chunk 5 / dec) is barriers away
    *(uint2*)(encbuf+(size_t)(tbprev+l15*4)*136+ccol)=hprev2;
  }

  // ================= decoder LSTM + projection =================
  bf16x8 wd[4][10]; f32x4 b4d[4];
  #pragma unroll
  for(int j=0;j<4;j++){
    float s=(j==2)?T2E:L2E;
    float4 bb=*(const float4*)(decb+(wv+j*8)*16+quad*4);
    b4d[j]=(f32x4){bb.x*s,bb.y*s,bb.z*s,bb.w*s};
    int nb=(wv+j*8)*16+l15;
    #pragma unroll
    for(int kt=0;kt<10;kt++){
      wd[j][kt]=*(const bf16x8*)(WU+DO_U+nb*320+kt*32+quad*8);
      pin(wd[j][kt]);
    }
  }
  // prologue: stage Xd(0); barrier also publishes enc's final h-flush
  if(tid>=256 && tid<288){ int q=tid-256; int rr=q>>1;
    const u16* src=WU+XD_U+((size_t)(b0+rr)*24+0)*16;
    u16* Xw=&Xdast[0][0];
    if(q&1) *(uint4*)(Xw+rr*72+8)=*(const uint4*)(src+8);
    else    *(uint4*)(Xw+rr*72)  =*(const uint4*)src; }
  __syncthreads();
  for(int t=0;t<24;t++){
    int tb=(t>>2)*64+(t&3);
    const u16* Ar=encbuf+(size_t)(tb+l15*4)*136;   // read-only in dec: no ordering needed
    const u16* Xd=&Xdast[t&1][0];
    const u16* Hb=&hstash[p][0];
    f32x4 acc[4];
    #pragma unroll
    for(int kt=0;kt<10;kt++){
      bf16x8 af=(kt<4)? *(const bf16x8*)(Ar+kt*32+quad*8)
              :(kt<6)? *(const bf16x8*)(Xd+l15*72+(kt-4)*32+quad*8)
                     : *(const bf16x8*)(Hb+l15*136+(kt-6)*32+quad*8);
      #pragma unroll
      for(int j=0;j<4;j++) acc[j]=MFMA(wd[j][kt],af,(kt==0)?b4d[j]:acc[j]);
    }
    // prefetch Xd(t+1) into opposite buffer: last reader was MFMA(t-1),
    // two barriers back -> race-free
    if(t<23 && tid>=256 && tid<288){ int q=tid-256; int rr=q>>1;
      const u16* src=WU+XD_U+((size_t)(b0+rr)*24+t+1)*16;
      u16* Xw=&Xdast[(t+1)&1][0];
      if(q&1) *(uint4*)(Xw+rr*72+8)=*(const uint4*)(src+8);
      else    *(uint4*)(Xw+rr*72)  =*(const uint4*)src; }
    uint2 hnew2;
    { float hf[4];
      #pragma unroll
      for(int reg=0;reg<4;reg++){
        float ig=sig2(acc[0][reg]),fg=sig2(acc[1][reg]);
        float gg=th2(acc[2][reg]), og=sig2(acc[3][reg]);
        float c_=__builtin_fmaf(fg,cst[reg],ig*gg); cst[reg]=c_;
        hf[reg]=og*thc(c_);
      }
      hnew2.x=f2b_pk(hf[0],hf[1]);
      hnew2.y=f2b_pk(hf[2],hf[3]);
    }
    int pn=p^1;
    *(uint2*)(&hstash[pn][0]+(size_t)l15*136+ccol)=hnew2;
    __syncthreads();      // projection needs the full new h row (+ Xd stage done)
    if(tid<128){ int row=tid>>3,g=tid&7; float s=0.f;
      #pragma unroll
      for(int i=0;i<16;i++) s+=b2f(hstash[pn][row*136+g*16+i])*outw_s[g*16+i];
      red[row][g]=s; }
    __syncthreads();
    if(tid<16){ float s=outb_s;
      #pragma unroll
      for(int g=0;g<8;g++) s+=red[tid][g];
      out[(b0+tid)*24+t]=s*scl_s[tid]; }
    p=pn;
  }
}

extern "C" void kernel_launch(void* const* d_in, const int* in_sizes, int n_in,
                              void* d_out, int out_size, void* d_ws, size_t ws_size,
                              hipStream_t stream)
{
  (void)in_sizes; (void)n_in; (void)out_size; (void)ws_size;
  const int*   cat  = (const int*)d_in[0];
  const float* sreal= (const float*)d_in[1];
  const float* ptf  = (const float*)d_in[2];
  const float* tgt  = (const float*)d_in[3];
  const float* obs  = (const float*)d_in[4];
  const float* ftf  = (const float*)d_in[5];
  const float* emb  = (const float*)d_in[6];
  const float* gWih = (const float*)d_in[7];
  const float* gWhh = (const float*)d_in[8];
  const float* gbih = (const float*)d_in[9];
  const float* gbhh = (const float*)d_in[10];
  const float* eWih = (const float*)d_in[11];
  const float* eWhh = (const float*)d_in[12];
  const float* encb = (const float*)d_in[13];
  const float* dWih = (const float*)d_in[14];
  const float* dWhh = (const float*)d_in[15];
  const float* decb = (const float*)d_in[16];
  const float* outW = (const float*)d_in[17];
  const float* outb = (const float*)d_in[18];
  float* ws  = (float*)d_ws;
  float* out = (float*)d_out;

  hipMemsetAsync(d_ws, 0, 2*sizeof(float), stream);
  scale_kernel<<<dim3(8192/256), dim3(256), 0, stream>>>(tgt, obs, ws);
  prep_w<<<dim3(512), dim3(256), 0, stream>>>(gWih,gWhh,eWih,eWhh,dWih,dWhh,ws);
  prep_x<<<dim3(128), dim3(256), 0, stream>>>(tgt, ptf, ftf, ws);
  deepar_main<<<dim3(512), dim3(512), 0, stream>>>(cat,sreal,emb,gbih,gbhh,encb,decb,
                                                   outW,outb,ws,out);
}